// Round 7
// baseline (112.619 us; speedup 1.0000x reference)
//
#include <hip/hip_runtime.h>
#include <hip/hip_bf16.h>

#define NN 4096

typedef unsigned short u16;
typedef __attribute__((ext_vector_type(8))) short bf16x8;
typedef __attribute__((ext_vector_type(4))) float f32x4;
typedef __attribute__((ext_vector_type(4))) unsigned u32x4;
typedef __attribute__((ext_vector_type(4))) unsigned short u16x4;

// fp32 -> bf16 round-to-nearest-even (inputs finite N(0,1))
static __device__ __forceinline__ u16 f2bf(float x) {
  unsigned u = __float_as_uint(x);
  u += 0x7fff + ((u >> 16) & 1);
  return (u16)(u >> 16);
}

// async global->LDS, 16B per lane; LDS dest = wave-uniform base + lane*16
static __device__ __forceinline__ void gload_lds16(const void* g, void* l) {
  __builtin_amdgcn_global_load_lds(
      (const __attribute__((address_space(1))) void*)g,
      (__attribute__((address_space(3))) void*)l, 16, 0, 0);
}

// F(M) = sum_{j=0}^{M-1} floor(j/CS): extra-chunk count for a row of M tiles
static __device__ __forceinline__ int Fpre(int M, int CS) {
  if (M <= 0) return 0;
  const int q = (M - 1) / CS, r = (M - 1) % CS;
  return CS * q * (q - 1) / 2 + q * (r + 1);
}

// ---------------------------------------------------------------------------
// Pass 1 (fused): blocks [0,1024): convert A (tril-masked bf16) for blocks
// kb<=bi, zero strict-upper C blocks for kb>bi. Blocks [1024,5120): convert
// B -> Bt (transposed, tril-masked bf16), skipping never-read blocks.
// All output stores nontemporal: data is consumed cross-XCD anyway (L3),
// and nt avoids write-allocate fetches.
// ---------------------------------------------------------------------------
__global__ __launch_bounds__(256) void convert_fused(
    const float* __restrict__ A, const float* __restrict__ B,
    u16* __restrict__ Ab, u16* __restrict__ Bt, float* __restrict__ C) {
  __shared__ float t[64][65];
  const int blk = blockIdx.x;
  const int tid = threadIdx.x;

  if (blk < 1024) {  // ---- A path: 128x128 block (bi, kb) ----
    const int kb = blk & 31, bi = blk >> 5;
    if (kb > bi) {  // zero C block (bi, kb)
      const f32x4 z = {0.f, 0.f, 0.f, 0.f};
      const int rr = tid >> 5, c4 = (tid & 31);
#pragma unroll
      for (int p = 0; p < 16; ++p)
        __builtin_nontemporal_store(
            z, (f32x4*)&C[(long)(bi * 128 + p * 8 + rr) * NN + kb * 128] + c4);
      return;
    }
    const int rr = tid >> 5;
    const int c4 = (tid & 31) * 4;
    const bool diag = (kb == bi);
#pragma unroll
    for (int p = 0; p < 16; ++p) {
      const int row = p * 8 + rr;
      const long off = (long)(bi * 128 + row) * NN + kb * 128 + c4;
      float4 v = *(const float4*)&A[off];
      u16x4 o;
      if (diag) {
        const int i = bi * 128 + row, k = kb * 128 + c4;
        o.x = (k + 0 <= i) ? f2bf(v.x) : (u16)0;
        o.y = (k + 1 <= i) ? f2bf(v.y) : (u16)0;
        o.z = (k + 2 <= i) ? f2bf(v.z) : (u16)0;
        o.w = (k + 3 <= i) ? f2bf(v.w) : (u16)0;
      } else {
        o.x = f2bf(v.x); o.y = f2bf(v.y); o.z = f2bf(v.z); o.w = f2bf(v.w);
      }
      __builtin_nontemporal_store(o, (u16x4*)&Ab[off]);
    }
    return;
  }

  // ---- B path: 64x64 transpose tile ----
  const int tb = blk - 1024;
  const int n64 = tb & 63;
  const int k64 = tb >> 6;
  if ((n64 >> 1) > (k64 >> 1)) return;

  const int n0 = n64 * 64;
  const int k0 = k64 * 64;

  if (n0 > k0 + 63) {  // read block, fully above diagonal -> zeros
    const int n = tid >> 3;
    const int kc = (tid & 7) * 8;
    const u32x4 z = {0u, 0u, 0u, 0u};
#pragma unroll
    for (int p = 0; p < 2; ++p)
      __builtin_nontemporal_store(
          z, (u32x4*)&Bt[(long)(n0 + n + p * 32) * NN + k0 + kc]);
    return;
  }

#pragma unroll
  for (int p = 0; p < 4; ++p) {
    const int r = (tid >> 4) + p * 16;
    const int c = (tid & 15) * 4;
    float4 v = *(const float4*)&B[(long)(k0 + r) * NN + n0 + c];
    const int kg = k0 + r;
    t[r][c + 0] = (n0 + c + 0 <= kg) ? v.x : 0.f;
    t[r][c + 1] = (n0 + c + 1 <= kg) ? v.y : 0.f;
    t[r][c + 2] = (n0 + c + 2 <= kg) ? v.z : 0.f;
    t[r][c + 3] = (n0 + c + 3 <= kg) ? v.w : 0.f;
  }
  __syncthreads();

#pragma unroll
  for (int p = 0; p < 2; ++p) {
    const int n = (tid >> 3) + p * 32;
    const int kc = (tid & 7) * 8;
    union { u16 h[8]; u32x4 v; } pk;
#pragma unroll
    for (int j = 0; j < 8; ++j) pk.h[j] = f2bf(t[kc + j][n]);
    __builtin_nontemporal_store(pk.v,
                                (u32x4*)&Bt[(long)(n0 + n) * NN + k0 + kc]);
  }
}

// ---------------------------------------------------------------------------
// Pass 2: lower-tri bf16 MFMA GEMM. m97 single-buffer structure (32 KB LDS ->
// 4-5 blocks/CU; cross-block TLP hides the barrier drain, m114). Static item
// grid: one block per (tile, chunk), decoded from a XCD-chunked remap of
// blockIdx.x (same-bi items share an XCD's L2 for the A panel). T2 swizzle:
// pre-swizzled global source column, XOR'd read slot -> 0 bank conflicts.
// Epilogue stores nontemporal (no write-allocate).
// ---------------------------------------------------------------------------
__global__ __launch_bounds__(256, 4) void gemm_tril(
    const u16* __restrict__ Ab, const u16* __restrict__ Bt,
    float* __restrict__ C, float* __restrict__ P, int CS, int nitems) {
  __shared__ u16 As[128 * 64];
  __shared__ u16 Bs[128 * 64];

  const int tid = threadIdx.x;
  const int lane = tid & 63;
  const int wid = tid >> 6;
  const int wm = wid >> 1;
  const int wn = wid & 1;
  const int sm = lane >> 3;               // staging row within 8-row chunk
  const int sks = ((lane & 7) ^ sm) * 8;  // pre-swizzled source col (u16)
  const int rsel = lane & 7;              // fragment row & 7

  // XCD-chunked remap (bijective: nitems % 8 == 0 for all tiers)
  const int item = ((nitems & 7) == 0)
                       ? (blockIdx.x & 7) * (nitems >> 3) + (blockIdx.x >> 3)
                       : blockIdx.x;

  // ---- decode item -> (bi, bj, chunk); rows longest-first ----
  int rem = item, s = 0;
  for (;;) {
    const int M = 32 - s;
    const int g = M + Fpre(M, CS);  // items in row s
    if (rem < g) break;
    rem -= g; ++s;
  }
  const int M = 32 - s;
  const int bi = 31 - s;
  int bj = 0;
  for (;;) {
    const int c = (M - bj + CS - 1) / CS;  // chunks of tile (bi,bj)
    if (rem < c) break;
    rem -= c; ++bj;
  }
  const int chunk = rem;
  const int L = M - bj;  // = bi - bj + 1

  f32x4 acc[4][4];
#pragma unroll
  for (int i = 0; i < 4; ++i)
#pragma unroll
    for (int j = 0; j < 4; ++j) acc[i][j] = (f32x4){0.f, 0.f, 0.f, 0.f};

  const int start = chunk * CS * 2;           // first K64-step
  const int nk = min(CS * 2, 2 * L - start);  // K64-steps in this chunk
  const int rA = bi * 128;
  const int rB = bj * 128;
  const long kbase = (long)bj * 128 + (long)start * 64;

  for (int kt = 0; kt < nk; ++kt) {
    const long k0 = kbase + (long)kt * 64;
#pragma unroll
    for (int c = 0; c < 4; ++c) {
      const int chnk = wid * 4 + c;  // 16 chunks of 8 rows x 64 bf16
      const int m = chnk * 8 + sm;
      gload_lds16(Ab + ((long)(rA + m) * NN + k0 + sks), &As[chnk * 512]);
      gload_lds16(Bt + ((long)(rB + m) * NN + k0 + sks), &Bs[chnk * 512]);
    }
    __syncthreads();  // compiler drains vmcnt(0); other blocks cover the stall

    bf16x8 a[2][4], b[2][4];
#pragma unroll
    for (int kk = 0; kk < 2; ++kk)
#pragma unroll
      for (int q = 0; q < 4; ++q) {
        const int fr = q * 16 + (lane & 15);                   // row in 64-blk
        const int slot = ((kk * 4 + (lane >> 4)) ^ rsel) * 8;  // swizzled col
        a[kk][q] = *(const bf16x8*)&As[(wm * 64 + fr) * 64 + slot];
        b[kk][q] = *(const bf16x8*)&Bs[(wn * 64 + fr) * 64 + slot];
      }
#pragma unroll
    for (int kk = 0; kk < 2; ++kk)
#pragma unroll
      for (int m4 = 0; m4 < 4; ++m4)
#pragma unroll
        for (int n4 = 0; n4 < 4; ++n4)
          acc[m4][n4] = __builtin_amdgcn_mfma_f32_16x16x32_bf16(
              a[kk][m4], b[kk][n4], acc[m4][n4], 0, 0, 0);
    __syncthreads();  // LDS free for next K-step
  }

  // ---- epilogue: C/D layout col=lane&15, row=(lane>>4)*4+r ----
  const int lrow = wm * 64 + (lane >> 4) * 4;
  const int lcol = wn * 64 + (lane & 15);
  if (chunk == 0) {
    const bool diag = (bi == bj);
#pragma unroll
    for (int m4 = 0; m4 < 4; ++m4)
#pragma unroll
      for (int n4 = 0; n4 < 4; ++n4)
#pragma unroll
        for (int r = 0; r < 4; ++r) {
          const int gi = rA + lrow + m4 * 16 + r;
          const int gj = rB + lcol + n4 * 16;
          float v = acc[m4][n4][r];
          if (diag && gj > gi) v = 0.f;
          __builtin_nontemporal_store(v, &C[(long)gi * NN + gj]);
        }
  } else {
    int off = 0;
    for (int sp = 0; sp < s; ++sp) off += Fpre(32 - sp, CS);
    off += Fpre(M, CS) - Fpre(M - bj, CS);
    float* slab = P + (long)(off + chunk - 1) * 16384;
#pragma unroll
    for (int m4 = 0; m4 < 4; ++m4)
#pragma unroll
      for (int n4 = 0; n4 < 4; ++n4)
#pragma unroll
        for (int r = 0; r < 4; ++r)
          __builtin_nontemporal_store(
              acc[m4][n4][r], &slab[(lrow + m4 * 16 + r) * 128 + lcol + n4 * 16]);
  }
}

// ---------------------------------------------------------------------------
// Pass 3: add partial slabs into C. Grid covers ONLY multi-chunk tiles
// (L > CS): (32-CS)(33-CS)/2 blocks.
// ---------------------------------------------------------------------------
__global__ __launch_bounds__(256) void reduce_partials(
    float* __restrict__ C, const float* __restrict__ P, int CS) {
  int rem = blockIdx.x, s = 0;
  for (;;) {
    const int g = 32 - s - CS;  // multi-chunk tiles in row s
    if (rem < g) break;
    rem -= g; ++s;
  }
  const int bj = rem;
  const int bi = 31 - s;
  const int M = 32 - s;
  const int L = M - bj;                  // >= CS+1
  const int nch = (L + CS - 1) / CS;     // >= 2
  int off = 0;
  for (int sp = 0; sp < s; ++sp) off += Fpre(32 - sp, CS);
  off += Fpre(M, CS) - Fpre(M - bj, CS);

  const int tid = threadIdx.x;
#pragma unroll
  for (int p = 0; p < 16; ++p) {
    const int idx = p * 256 + tid;
    const int row = idx >> 5;
    const int col = (idx & 31) * 4;
    const long coff = (long)(bi * 128 + row) * NN + bj * 128 + col;
    float4 acc = *(const float4*)&C[coff];
    for (int e = 0; e < nch - 1; ++e) {
      const float4 q =
          *(const float4*)&P[(long)(off + e) * 16384 + row * 128 + col];
      acc.x += q.x; acc.y += q.y; acc.z += q.z; acc.w += q.w;
    }
    const f32x4 o = {acc.x, acc.y, acc.z, acc.w};
    __builtin_nontemporal_store(o, (f32x4*)&C[coff]);
  }
}

// ---------------------------------------------------------------------------
// Fallback (ws too small): naive fp32.
// ---------------------------------------------------------------------------
__global__ void naive_tril(const float* __restrict__ A,
                           const float* __restrict__ B, float* __restrict__ C) {
  const int j = blockIdx.x * 256 + threadIdx.x;
  const int i = blockIdx.y;
  float s = 0.f;
  for (int k = j; k <= i; ++k) s += A[(long)i * NN + k] * B[(long)k * NN + j];
  C[(long)i * NN + j] = s;
}

extern "C" void kernel_launch(void* const* d_in, const int* in_sizes, int n_in,
                              void* d_out, int out_size, void* d_ws,
                              size_t ws_size, hipStream_t stream) {
  const float* A = (const float*)d_in[0];
  const float* B = (const float*)d_in[1];
  float* C = (float*)d_out;

  const size_t opbytes = (size_t)2 * NN * NN * sizeof(u16);  // 64 MB operands
  // tiers: CS=8 -> 472 slabs (1000 items), CS=16 -> 136 (664), CS=32 -> 0
  const size_t need8 = opbytes + (size_t)472 * 65536;
  const size_t need16 = opbytes + (size_t)136 * 65536;

  if (ws_size < opbytes) {
    naive_tril<<<dim3(16, NN), 256, 0, stream>>>(A, B, C);
    return;
  }

  int CS, nslab, nitems;
  if (ws_size >= need8)       { CS = 8;  nslab = 472; nitems = 1000; }
  else if (ws_size >= need16) { CS = 16; nslab = 136; nitems = 664; }
  else                        { CS = 32; nslab = 0;   nitems = 528; }

  u16* Ab = (u16*)d_ws;
  u16* Bt = Ab + (long)NN * NN;
  float* P = (float*)((char*)d_ws + opbytes);

  convert_fused<<<5120, 256, 0, stream>>>(A, B, Ab, Bt, C);
  gemm_tril<<<nitems, 256, 0, stream>>>(Ab, Bt, C, P, CS, nitems);
  if (nslab > 0) {
    const int nred = (32 - CS) * (33 - CS) / 2;  // 300 (CS=8) / 136 (CS=16)
    reduce_partials<<<nred, 256, 0, stream>>>(C, P, CS);
  }
}

// Round 8
// 102.458 us; speedup vs baseline: 1.0992x; 1.0992x over previous
//
#include <hip/hip_runtime.h>
#include <hip/hip_bf16.h>

#define NN 4096

typedef unsigned short u16;
typedef __attribute__((ext_vector_type(8))) short bf16x8;
typedef __attribute__((ext_vector_type(4))) float f32x4;

// fp32 -> bf16 round-to-nearest-even (inputs finite N(0,1))
static __device__ __forceinline__ u16 f2bf(float x) {
  unsigned u = __float_as_uint(x);
  u += 0x7fff + ((u >> 16) & 1);
  return (u16)(u >> 16);
}

// async global->LDS, 16B per lane; LDS dest = wave-uniform base + lane*16
static __device__ __forceinline__ void gload_lds16(const void* g, void* l) {
  __builtin_amdgcn_global_load_lds(
      (const __attribute__((address_space(1))) void*)g,
      (__attribute__((address_space(3))) void*)l, 16, 0, 0);
}

// F(M) = sum_{j=0}^{M-1} floor(j/CS): extra-chunk count for a row of M tiles
static __device__ __forceinline__ int Fpre(int M, int CS) {
  if (M <= 0) return 0;
  const int q = (M - 1) / CS, r = (M - 1) % CS;
  return CS * q * (q - 1) / 2 + q * (r + 1);
}

// ---------------------------------------------------------------------------
// Pass 1 (fused): blocks [0,1024): convert A (tril-masked bf16) for blocks
// kb<=bi, zero strict-upper C blocks for kb>bi. Blocks [1024,5120): convert
// B -> Bt (transposed, tril-masked bf16), skipping never-read blocks.
// Plain stores: operands/C stay in L2/L3 for the consumer passes (nt stores
// measured -13 us in round 7).
// ---------------------------------------------------------------------------
__global__ __launch_bounds__(256) void convert_fused(
    const float* __restrict__ A, const float* __restrict__ B,
    u16* __restrict__ Ab, u16* __restrict__ Bt, float* __restrict__ C) {
  __shared__ float t[64][65];
  const int blk = blockIdx.x;
  const int tid = threadIdx.x;

  if (blk < 1024) {  // ---- A path: 128x128 block (bi, kb) ----
    const int kb = blk & 31, bi = blk >> 5;
    if (kb > bi) {  // zero C block (bi, kb)
      const float4 z = {0.f, 0.f, 0.f, 0.f};
      const int rr = tid >> 5, c4 = (tid & 31);
#pragma unroll
      for (int p = 0; p < 16; ++p)
        ((float4*)&C[(long)(bi * 128 + p * 8 + rr) * NN + kb * 128])[c4] = z;
      return;
    }
    const int rr = tid >> 5;
    const int c4 = (tid & 31) * 4;
    const bool diag = (kb == bi);
#pragma unroll
    for (int p = 0; p < 16; ++p) {
      const int row = p * 8 + rr;
      const long off = (long)(bi * 128 + row) * NN + kb * 128 + c4;
      float4 v = *(const float4*)&A[off];
      ushort4 o;
      if (diag) {
        const int i = bi * 128 + row, k = kb * 128 + c4;
        o.x = (k + 0 <= i) ? f2bf(v.x) : (u16)0;
        o.y = (k + 1 <= i) ? f2bf(v.y) : (u16)0;
        o.z = (k + 2 <= i) ? f2bf(v.z) : (u16)0;
        o.w = (k + 3 <= i) ? f2bf(v.w) : (u16)0;
      } else {
        o.x = f2bf(v.x); o.y = f2bf(v.y); o.z = f2bf(v.z); o.w = f2bf(v.w);
      }
      *(ushort4*)&Ab[off] = o;
    }
    return;
  }

  // ---- B path: 64x64 transpose tile ----
  const int tb = blk - 1024;
  const int n64 = tb & 63;
  const int k64 = tb >> 6;
  if ((n64 >> 1) > (k64 >> 1)) return;

  const int n0 = n64 * 64;
  const int k0 = k64 * 64;

  if (n0 > k0 + 63) {  // read block, fully above diagonal -> zeros
    const int n = tid >> 3;
    const int kc = (tid & 7) * 8;
    const uint4 z = {0u, 0u, 0u, 0u};
#pragma unroll
    for (int p = 0; p < 2; ++p)
      *(uint4*)&Bt[(long)(n0 + n + p * 32) * NN + k0 + kc] = z;
    return;
  }

#pragma unroll
  for (int p = 0; p < 4; ++p) {
    const int r = (tid >> 4) + p * 16;
    const int c = (tid & 15) * 4;
    float4 v = *(const float4*)&B[(long)(k0 + r) * NN + n0 + c];
    const int kg = k0 + r;
    t[r][c + 0] = (n0 + c + 0 <= kg) ? v.x : 0.f;
    t[r][c + 1] = (n0 + c + 1 <= kg) ? v.y : 0.f;
    t[r][c + 2] = (n0 + c + 2 <= kg) ? v.z : 0.f;
    t[r][c + 3] = (n0 + c + 3 <= kg) ? v.w : 0.f;
  }
  __syncthreads();

#pragma unroll
  for (int p = 0; p < 2; ++p) {
    const int n = (tid >> 3) + p * 32;
    const int kc = (tid & 7) * 8;
    union { u16 h[8]; uint4 v; } pk;
#pragma unroll
    for (int j = 0; j < 8; ++j) pk.h[j] = f2bf(t[kc + j][n]);
    *(uint4*)&Bt[(long)(n0 + n) * NN + k0 + kc] = pk.v;
  }
}

// ---------------------------------------------------------------------------
// Pass 2: lower-tri bf16 MFMA GEMM. m97 single-buffer structure (32 KB LDS ->
// 4-5 blocks/CU; cross-block TLP hides the barrier drain, m114). Static item
// grid: one block per (tile, chunk), item = blockIdx.x IDENTITY in
// longest-K-first order -- hardware round-robin over XCDs then balances
// lengths across XCDs automatically (the round-6 remap overloaded XCD0 with
// all the longest chunks: ~33% imbalance, worth ~12-15 us). T2 swizzle:
// pre-swizzled global source column, XOR'd read slot -> 0 bank conflicts.
// ---------------------------------------------------------------------------
__global__ __launch_bounds__(256, 4) void gemm_tril(
    const u16* __restrict__ Ab, const u16* __restrict__ Bt,
    float* __restrict__ C, float* __restrict__ P, int CS) {
  __shared__ u16 As[128 * 64];
  __shared__ u16 Bs[128 * 64];

  const int tid = threadIdx.x;
  const int lane = tid & 63;
  const int wid = tid >> 6;
  const int wm = wid >> 1;
  const int wn = wid & 1;
  const int sm = lane >> 3;               // staging row within 8-row chunk
  const int sks = ((lane & 7) ^ sm) * 8;  // pre-swizzled source col (u16)
  const int rsel = lane & 7;              // fragment row & 7

  // ---- decode blockIdx.x -> (bi, bj, chunk); rows longest-first ----
  int rem = blockIdx.x, s = 0;
  for (;;) {
    const int M = 32 - s;
    const int g = M + Fpre(M, CS);  // items in row s
    if (rem < g) break;
    rem -= g; ++s;
  }
  const int M = 32 - s;
  const int bi = 31 - s;
  int bj = 0;
  for (;;) {
    const int c = (M - bj + CS - 1) / CS;  // chunks of tile (bi,bj)
    if (rem < c) break;
    rem -= c; ++bj;
  }
  const int chunk = rem;
  const int L = M - bj;  // = bi - bj + 1

  f32x4 acc[4][4];
#pragma unroll
  for (int i = 0; i < 4; ++i)
#pragma unroll
    for (int j = 0; j < 4; ++j) acc[i][j] = (f32x4){0.f, 0.f, 0.f, 0.f};

  const int start = chunk * CS * 2;           // first K64-step
  const int nk = min(CS * 2, 2 * L - start);  // K64-steps in this chunk
  const int rA = bi * 128;
  const int rB = bj * 128;
  const long kbase = (long)bj * 128 + (long)start * 64;

  for (int kt = 0; kt < nk; ++kt) {
    const long k0 = kbase + (long)kt * 64;
#pragma unroll
    for (int c = 0; c < 4; ++c) {
      const int chnk = wid * 4 + c;  // 16 chunks of 8 rows x 64 bf16
      const int m = chnk * 8 + sm;
      gload_lds16(Ab + ((long)(rA + m) * NN + k0 + sks), &As[chnk * 512]);
      gload_lds16(Bt + ((long)(rB + m) * NN + k0 + sks), &Bs[chnk * 512]);
    }
    __syncthreads();  // compiler drains vmcnt(0); co-resident blocks cover it

    bf16x8 a[2][4], b[2][4];
#pragma unroll
    for (int kk = 0; kk < 2; ++kk)
#pragma unroll
      for (int q = 0; q < 4; ++q) {
        const int fr = q * 16 + (lane & 15);                   // row in 64-blk
        const int slot = ((kk * 4 + (lane >> 4)) ^ rsel) * 8;  // swizzled col
        a[kk][q] = *(const bf16x8*)&As[(wm * 64 + fr) * 64 + slot];
        b[kk][q] = *(const bf16x8*)&Bs[(wn * 64 + fr) * 64 + slot];
      }
#pragma unroll
    for (int kk = 0; kk < 2; ++kk)
#pragma unroll
      for (int m4 = 0; m4 < 4; ++m4)
#pragma unroll
        for (int n4 = 0; n4 < 4; ++n4)
          acc[m4][n4] = __builtin_amdgcn_mfma_f32_16x16x32_bf16(
              a[kk][m4], b[kk][n4], acc[m4][n4], 0, 0, 0);
    __syncthreads();  // LDS free for next K-step
  }

  // ---- epilogue: C/D layout col=lane&15, row=(lane>>4)*4+r ----
  const int lrow = wm * 64 + (lane >> 4) * 4;
  const int lcol = wn * 64 + (lane & 15);
  if (chunk == 0) {
    const bool diag = (bi == bj);
#pragma unroll
    for (int m4 = 0; m4 < 4; ++m4)
#pragma unroll
      for (int n4 = 0; n4 < 4; ++n4)
#pragma unroll
        for (int r = 0; r < 4; ++r) {
          const int gi = rA + lrow + m4 * 16 + r;
          const int gj = rB + lcol + n4 * 16;
          float v = acc[m4][n4][r];
          if (diag && gj > gi) v = 0.f;
          C[(long)gi * NN + gj] = v;
        }
  } else {
    int off = 0;
    for (int sp = 0; sp < s; ++sp) off += Fpre(32 - sp, CS);
    off += Fpre(M, CS) - Fpre(M - bj, CS);
    float* slab = P + (long)(off + chunk - 1) * 16384;
#pragma unroll
    for (int m4 = 0; m4 < 4; ++m4)
#pragma unroll
      for (int n4 = 0; n4 < 4; ++n4)
#pragma unroll
        for (int r = 0; r < 4; ++r)
          slab[(lrow + m4 * 16 + r) * 128 + lcol + n4 * 16] = acc[m4][n4][r];
  }
}

// ---------------------------------------------------------------------------
// Pass 3: add partial slabs into C. Grid covers ONLY multi-chunk tiles
// (L > CS): (32-CS)(33-CS)/2 blocks.
// ---------------------------------------------------------------------------
__global__ __launch_bounds__(256) void reduce_partials(
    float* __restrict__ C, const float* __restrict__ P, int CS) {
  int rem = blockIdx.x, s = 0;
  for (;;) {
    const int g = 32 - s - CS;  // multi-chunk tiles in row s
    if (rem < g) break;
    rem -= g; ++s;
  }
  const int bj = rem;
  const int bi = 31 - s;
  const int M = 32 - s;
  const int L = M - bj;               // >= CS+1
  const int nch = (L + CS - 1) / CS;  // >= 2
  int off = 0;
  for (int sp = 0; sp < s; ++sp) off += Fpre(32 - sp, CS);
  off += Fpre(M, CS) - Fpre(M - bj, CS);

  const int tid = threadIdx.x;
#pragma unroll
  for (int p = 0; p < 16; ++p) {
    const int idx = p * 256 + tid;
    const int row = idx >> 5;
    const int col = (idx & 31) * 4;
    const long coff = (long)(bi * 128 + row) * NN + bj * 128 + col;
    float4 acc = *(const float4*)&C[coff];
    for (int e = 0; e < nch - 1; ++e) {
      const float4 q =
          *(const float4*)&P[(long)(off + e) * 16384 + row * 128 + col];
      acc.x += q.x; acc.y += q.y; acc.z += q.z; acc.w += q.w;
    }
    *(float4*)&C[coff] = acc;
  }
}

// ---------------------------------------------------------------------------
// Fallback (ws too small): naive fp32.
// ---------------------------------------------------------------------------
__global__ void naive_tril(const float* __restrict__ A,
                           const float* __restrict__ B, float* __restrict__ C) {
  const int j = blockIdx.x * 256 + threadIdx.x;
  const int i = blockIdx.y;
  float s = 0.f;
  for (int k = j; k <= i; ++k) s += A[(long)i * NN + k] * B[(long)k * NN + j];
  C[(long)i * NN + j] = s;
}

extern "C" void kernel_launch(void* const* d_in, const int* in_sizes, int n_in,
                              void* d_out, int out_size, void* d_ws,
                              size_t ws_size, hipStream_t stream) {
  const float* A = (const float*)d_in[0];
  const float* B = (const float*)d_in[1];
  float* C = (float*)d_out;

  const size_t opbytes = (size_t)2 * NN * NN * sizeof(u16);  // 64 MB operands
  // tiers: CS=8 -> 472 slabs (1000 items), CS=16 -> 136 (664), CS=32 -> 0
  const size_t need8 = opbytes + (size_t)472 * 65536;
  const size_t need16 = opbytes + (size_t)136 * 65536;

  if (ws_size < opbytes) {
    naive_tril<<<dim3(16, NN), 256, 0, stream>>>(A, B, C);
    return;
  }

  int CS, nslab, nitems;
  if (ws_size >= need8)       { CS = 8;  nslab = 472; nitems = 1000; }
  else if (ws_size >= need16) { CS = 16; nslab = 136; nitems = 664; }
  else                        { CS = 32; nslab = 0;   nitems = 528; }

  u16* Ab = (u16*)d_ws;
  u16* Bt = Ab + (long)NN * NN;
  float* P = (float*)((char*)d_ws + opbytes);

  convert_fused<<<5120, 256, 0, stream>>>(A, B, Ab, Bt, C);
  gemm_tril<<<nitems, 256, 0, stream>>>(Ab, Bt, C, P, CS);
  if (nslab > 0) {
    const int nred = (32 - CS) * (33 - CS) / 2;  // 300 (CS=8) / 136 (CS=16)
    reduce_partials<<<nred, 256, 0, stream>>>(C, P, CS);
  }
}

// Round 9
// 97.026 us; speedup vs baseline: 1.1607x; 1.0560x over previous
//
#include <hip/hip_runtime.h>
#include <hip/hip_bf16.h>

#define NN 4096

typedef unsigned short u16;
typedef __attribute__((ext_vector_type(8))) short bf16x8;
typedef __attribute__((ext_vector_type(4))) float f32x4;

// fp32 -> bf16 round-to-nearest-even (inputs finite N(0,1))
static __device__ __forceinline__ u16 f2bf(float x) {
  unsigned u = __float_as_uint(x);
  u += 0x7fff + ((u >> 16) & 1);
  return (u16)(u >> 16);
}

// async global->LDS, 16B per lane; LDS dest = wave-uniform base + lane*16
static __device__ __forceinline__ void gload_lds16(const void* g, void* l) {
  __builtin_amdgcn_global_load_lds(
      (const __attribute__((address_space(1))) void*)g,
      (__attribute__((address_space(3))) void*)l, 16, 0, 0);
}

// F(M) = sum_{j=0}^{M-1} floor(j/CS): extra-chunk count for a row of M tiles
static __device__ __forceinline__ int Fpre(int M, int CS) {
  if (M <= 0) return 0;
  const int q = (M - 1) / CS, r = (M - 1) % CS;
  return CS * q * (q - 1) / 2 + q * (r + 1);
}

// ---------------------------------------------------------------------------
// Pass 1 (fused): blocks [0,1024): convert A (tril-masked bf16) for blocks
// kb<=bi, zero strict-upper C blocks for kb>bi. Blocks [1024,5120): convert
// B -> Bt (transposed, tril-masked bf16), skipping never-read blocks.
// ---------------------------------------------------------------------------
__global__ __launch_bounds__(256) void convert_fused(
    const float* __restrict__ A, const float* __restrict__ B,
    u16* __restrict__ Ab, u16* __restrict__ Bt, float* __restrict__ C) {
  __shared__ float t[64][65];
  const int blk = blockIdx.x;
  const int tid = threadIdx.x;

  if (blk < 1024) {  // ---- A path: 128x128 block (bi, kb) ----
    const int kb = blk & 31, bi = blk >> 5;
    if (kb > bi) {  // zero C block (bi, kb)
      const float4 z = {0.f, 0.f, 0.f, 0.f};
      const int rr = tid >> 5, c4 = (tid & 31);
#pragma unroll
      for (int p = 0; p < 16; ++p)
        ((float4*)&C[(long)(bi * 128 + p * 8 + rr) * NN + kb * 128])[c4] = z;
      return;
    }
    const int rr = tid >> 5;
    const int c4 = (tid & 31) * 4;
    const bool diag = (kb == bi);
#pragma unroll
    for (int p = 0; p < 16; ++p) {
      const int row = p * 8 + rr;
      const long off = (long)(bi * 128 + row) * NN + kb * 128 + c4;
      float4 v = *(const float4*)&A[off];
      ushort4 o;
      if (diag) {
        const int i = bi * 128 + row, k = kb * 128 + c4;
        o.x = (k + 0 <= i) ? f2bf(v.x) : (u16)0;
        o.y = (k + 1 <= i) ? f2bf(v.y) : (u16)0;
        o.z = (k + 2 <= i) ? f2bf(v.z) : (u16)0;
        o.w = (k + 3 <= i) ? f2bf(v.w) : (u16)0;
      } else {
        o.x = f2bf(v.x); o.y = f2bf(v.y); o.z = f2bf(v.z); o.w = f2bf(v.w);
      }
      *(ushort4*)&Ab[off] = o;
    }
    return;
  }

  // ---- B path: 64x64 transpose tile ----
  const int tb = blk - 1024;
  const int n64 = tb & 63;
  const int k64 = tb >> 6;
  if ((n64 >> 1) > (k64 >> 1)) return;

  const int n0 = n64 * 64;
  const int k0 = k64 * 64;

  if (n0 > k0 + 63) {  // read block, fully above diagonal -> zeros
    const int n = tid >> 3;
    const int kc = (tid & 7) * 8;
    const uint4 z = {0u, 0u, 0u, 0u};
#pragma unroll
    for (int p = 0; p < 2; ++p)
      *(uint4*)&Bt[(long)(n0 + n + p * 32) * NN + k0 + kc] = z;
    return;
  }

#pragma unroll
  for (int p = 0; p < 4; ++p) {
    const int r = (tid >> 4) + p * 16;
    const int c = (tid & 15) * 4;
    float4 v = *(const float4*)&B[(long)(k0 + r) * NN + n0 + c];
    const int kg = k0 + r;
    t[r][c + 0] = (n0 + c + 0 <= kg) ? v.x : 0.f;
    t[r][c + 1] = (n0 + c + 1 <= kg) ? v.y : 0.f;
    t[r][c + 2] = (n0 + c + 2 <= kg) ? v.z : 0.f;
    t[r][c + 3] = (n0 + c + 3 <= kg) ? v.w : 0.f;
  }
  __syncthreads();

#pragma unroll
  for (int p = 0; p < 2; ++p) {
    const int n = (tid >> 3) + p * 32;
    const int kc = (tid & 7) * 8;
    union { u16 h[8]; uint4 v; } pk;
#pragma unroll
    for (int j = 0; j < 8; ++j) pk.h[j] = f2bf(t[kc + j][n]);
    *(uint4*)&Bt[(long)(n0 + n) * NN + k0 + kc] = pk.v;
  }
}

// ---------------------------------------------------------------------------
// Pass 2: lower-tri bf16 MFMA GEMM. Composition of the two proven pieces:
//   - R4's 2-phase pipeline: double-buffered LDS (64 KB = exactly 2
//     blocks/CU), STAGE(t+1) issued BEFORE compute(t), counted
//     s_waitcnt vmcnt(8) (prefetch never drained in-loop), raw s_barrier.
//   - R6's T2 swizzle: pre-swizzled global source column (gload_lds writes
//     linearly), XOR'd read slot -> 0 bank conflicts (without this the
//     16-way conflict serialization masks the pipeline's gain, m252).
// Static item grid (no atomics/LDS broadcast), XCD-chunked remap (R6/R7:
// ~2% win). Fences per rule #18: sched_barrier(0) after waits.
// ---------------------------------------------------------------------------
__global__ __launch_bounds__(256, 4) void gemm_tril(
    const u16* __restrict__ Ab, const u16* __restrict__ Bt,
    float* __restrict__ C, float* __restrict__ P, int CS, int nitems) {
  __shared__ u16 As[2][128 * 64];
  __shared__ u16 Bs[2][128 * 64];

  const int tid = threadIdx.x;
  const int lane = tid & 63;
  const int wid = tid >> 6;
  const int wm = wid >> 1;
  const int wn = wid & 1;
  const int sm = lane >> 3;               // staging row within 8-row chunk
  const int sks = ((lane & 7) ^ sm) * 8;  // pre-swizzled source col (u16)
  const int rsel = lane & 7;              // fragment row & 7

  // XCD-chunked remap (bijective: nitems % 8 == 0 for all tiers)
  const int item = ((nitems & 7) == 0)
                       ? (blockIdx.x & 7) * (nitems >> 3) + (blockIdx.x >> 3)
                       : blockIdx.x;

  // ---- decode item -> (bi, bj, chunk); rows longest-first ----
  int rem = item, s = 0;
  for (;;) {
    const int M = 32 - s;
    const int g = M + Fpre(M, CS);  // items in row s
    if (rem < g) break;
    rem -= g; ++s;
  }
  const int M = 32 - s;
  const int bi = 31 - s;
  int bj = 0;
  for (;;) {
    const int c = (M - bj + CS - 1) / CS;  // chunks of tile (bi,bj)
    if (rem < c) break;
    rem -= c; ++bj;
  }
  const int chunk = rem;
  const int L = M - bj;  // = bi - bj + 1

  f32x4 acc[4][4];
#pragma unroll
  for (int i = 0; i < 4; ++i)
#pragma unroll
    for (int j = 0; j < 4; ++j) acc[i][j] = (f32x4){0.f, 0.f, 0.f, 0.f};

  const int start = chunk * CS * 2;           // first K64-step
  const int nk = min(CS * 2, 2 * L - start);  // K64-steps in this chunk
  const int rA = bi * 128;
  const int rB = bj * 128;
  const long kbase = (long)bj * 128 + (long)start * 64;

  // stage K64-step (start+kt) into buffer b: 8 gload_lds16 per thread
#define STAGE(kt, b)                                                          \
  do {                                                                        \
    const long k0 = kbase + (long)(kt)*64;                                    \
    _Pragma("unroll") for (int c = 0; c < 4; ++c) {                           \
      const int chnk = wid * 4 + c;                                           \
      const int m = chnk * 8 + sm;                                            \
      gload_lds16(Ab + ((long)(rA + m) * NN + k0 + sks), &As[b][chnk * 512]); \
      gload_lds16(Bt + ((long)(rB + m) * NN + k0 + sks), &Bs[b][chnk * 512]); \
    }                                                                         \
  } while (0)

  STAGE(0, 0);

  for (int kt = 0; kt < nk; ++kt) {
    const int cur = kt & 1;
    if (kt + 1 < nk) {
      STAGE(kt + 1, cur ^ 1);  // prefetch: stays in flight across barrier
      asm volatile("s_waitcnt vmcnt(8)" ::: "memory");  // cur's 8 landed
    } else {
      asm volatile("s_waitcnt vmcnt(0)" ::: "memory");
    }
    __builtin_amdgcn_s_barrier();        // all waves' cur-stage complete
    __builtin_amdgcn_sched_barrier(0);   // no ds_read hoist above barrier

    bf16x8 a[2][4], b[2][4];
#pragma unroll
    for (int kk = 0; kk < 2; ++kk)
#pragma unroll
      for (int q = 0; q < 4; ++q) {
        const int fr = q * 16 + (lane & 15);                   // row in 64-blk
        const int slot = ((kk * 4 + (lane >> 4)) ^ rsel) * 8;  // swizzled col
        a[kk][q] = *(const bf16x8*)&As[cur][(wm * 64 + fr) * 64 + slot];
        b[kk][q] = *(const bf16x8*)&Bs[cur][(wn * 64 + fr) * 64 + slot];
      }
#pragma unroll
    for (int kk = 0; kk < 2; ++kk)
#pragma unroll
      for (int m4 = 0; m4 < 4; ++m4)
#pragma unroll
        for (int n4 = 0; n4 < 4; ++n4)
          acc[m4][n4] = __builtin_amdgcn_mfma_f32_16x16x32_bf16(
              a[kk][m4], b[kk][n4], acc[m4][n4], 0, 0, 0);

    // all LDS reads of buf[cur] landed in registers before any wave's next
    // STAGE can overwrite it (rule #18 fence + barrier)
    asm volatile("s_waitcnt lgkmcnt(0)" ::: "memory");
    __builtin_amdgcn_sched_barrier(0);
    __builtin_amdgcn_s_barrier();
  }
#undef STAGE

  // ---- epilogue: C/D layout col=lane&15, row=(lane>>4)*4+r ----
  const int lrow = wm * 64 + (lane >> 4) * 4;
  const int lcol = wn * 64 + (lane & 15);
  if (chunk == 0) {
    const bool diag = (bi == bj);
#pragma unroll
    for (int m4 = 0; m4 < 4; ++m4)
#pragma unroll
      for (int n4 = 0; n4 < 4; ++n4)
#pragma unroll
        for (int r = 0; r < 4; ++r) {
          const int gi = rA + lrow + m4 * 16 + r;
          const int gj = rB + lcol + n4 * 16;
          float v = acc[m4][n4][r];
          if (diag && gj > gi) v = 0.f;
          C[(long)gi * NN + gj] = v;
        }
  } else {
    int off = 0;
    for (int sp = 0; sp < s; ++sp) off += Fpre(32 - sp, CS);
    off += Fpre(M, CS) - Fpre(M - bj, CS);
    float* slab = P + (long)(off + chunk - 1) * 16384;
#pragma unroll
    for (int m4 = 0; m4 < 4; ++m4)
#pragma unroll
      for (int n4 = 0; n4 < 4; ++n4)
#pragma unroll
        for (int r = 0; r < 4; ++r)
          slab[(lrow + m4 * 16 + r) * 128 + lcol + n4 * 16] = acc[m4][n4][r];
  }
}

// ---------------------------------------------------------------------------
// Pass 3: add partial slabs into C. Grid covers ONLY multi-chunk tiles
// (L > CS): (32-CS)(33-CS)/2 blocks.
// ---------------------------------------------------------------------------
__global__ __launch_bounds__(256) void reduce_partials(
    float* __restrict__ C, const float* __restrict__ P, int CS) {
  int rem = blockIdx.x, s = 0;
  for (;;) {
    const int g = 32 - s - CS;  // multi-chunk tiles in row s
    if (rem < g) break;
    rem -= g; ++s;
  }
  const int bj = rem;
  const int bi = 31 - s;
  const int M = 32 - s;
  const int L = M - bj;               // >= CS+1
  const int nch = (L + CS - 1) / CS;  // >= 2
  int off = 0;
  for (int sp = 0; sp < s; ++sp) off += Fpre(32 - sp, CS);
  off += Fpre(M, CS) - Fpre(M - bj, CS);

  const int tid = threadIdx.x;
#pragma unroll
  for (int p = 0; p < 16; ++p) {
    const int idx = p * 256 + tid;
    const int row = idx >> 5;
    const int col = (idx & 31) * 4;
    const long coff = (long)(bi * 128 + row) * NN + bj * 128 + col;
    float4 acc = *(const float4*)&C[coff];
    for (int e = 0; e < nch - 1; ++e) {
      const float4 q =
          *(const float4*)&P[(long)(off + e) * 16384 + row * 128 + col];
      acc.x += q.x; acc.y += q.y; acc.z += q.z; acc.w += q.w;
    }
    *(float4*)&C[coff] = acc;
  }
}

// ---------------------------------------------------------------------------
// Fallback (ws too small): naive fp32.
// ---------------------------------------------------------------------------
__global__ void naive_tril(const float* __restrict__ A,
                           const float* __restrict__ B, float* __restrict__ C) {
  const int j = blockIdx.x * 256 + threadIdx.x;
  const int i = blockIdx.y;
  float s = 0.f;
  for (int k = j; k <= i; ++k) s += A[(long)i * NN + k] * B[(long)k * NN + j];
  C[(long)i * NN + j] = s;
}

extern "C" void kernel_launch(void* const* d_in, const int* in_sizes, int n_in,
                              void* d_out, int out_size, void* d_ws,
                              size_t ws_size, hipStream_t stream) {
  const float* A = (const float*)d_in[0];
  const float* B = (const float*)d_in[1];
  float* C = (float*)d_out;

  const size_t opbytes = (size_t)2 * NN * NN * sizeof(u16);  // 64 MB operands
  // tiers: CS=8 -> 472 slabs (1000 items), CS=16 -> 136 (664), CS=32 -> 0
  const size_t need8 = opbytes + (size_t)472 * 65536;
  const size_t need16 = opbytes + (size_t)136 * 65536;

  if (ws_size < opbytes) {
    naive_tril<<<dim3(16, NN), 256, 0, stream>>>(A, B, C);
    return;
  }

  int CS, nslab, nitems;
  if (ws_size >= need8)       { CS = 8;  nslab = 472; nitems = 1000; }
  else if (ws_size >= need16) { CS = 16; nslab = 136; nitems = 664; }
  else                        { CS = 32; nslab = 0;   nitems = 528; }

  u16* Ab = (u16*)d_ws;
  u16* Bt = Ab + (long)NN * NN;
  float* P = (float*)((char*)d_ws + opbytes);

  convert_fused<<<5120, 256, 0, stream>>>(A, B, Ab, Bt, C);
  gemm_tril<<<nitems, 256, 0, stream>>>(Ab, Bt, C, P, CS, nitems);
  if (nslab > 0) {
    const int nred = (32 - CS) * (33 - CS) / 2;  // 300 (CS=8) / 136 (CS=16)
    reduce_partials<<<nred, 256, 0, stream>>>(C, P, CS);
  }
}